// Round 4
// baseline (444.058 us; speedup 1.0000x reference)
//
#include <hip/hip_runtime.h>

#define DM   1024
#define DI   2048
#define LSEQ 1024
#define BSZ  2
#define MROWS (BSZ*LSEQ)   // 2048

typedef __attribute__((ext_vector_type(4))) float  f32x4;
typedef __attribute__((ext_vector_type(8))) __bf16 bf16x8;

__device__ __forceinline__ unsigned short f2bf(float f) {
  union { float f; unsigned int u; } v; v.f = f;
  unsigned int u = v.u;
  unsigned int r = (u + 0x7fffu + ((u >> 16) & 1u)) >> 16;  // RNE
  return (unsigned short)r;
}

__device__ __forceinline__ void load_lds16(const void* g, void* l) {
  __builtin_amdgcn_global_load_lds((const __attribute__((address_space(1))) void*)g,
                                   (__attribute__((address_space(3))) void*)l, 16, 0, 0);
}

// ---------------- LayerNorm + cast to bf16 ----------------
__global__ __launch_bounds__(256) void ln_cast(const float* __restrict__ x,
    const float* __restrict__ w, const float* __restrict__ b,
    unsigned short* __restrict__ out)
{
  int row = blockIdx.x, tid = threadIdx.x;
  const float4* xr = (const float4*)(x + (size_t)row * DM);
  float4 v = xr[tid];
  float s  = v.x + v.y + v.z + v.w;
  float s2 = v.x*v.x + v.y*v.y + v.z*v.z + v.w*v.w;
  #pragma unroll
  for (int off = 32; off > 0; off >>= 1) { s += __shfl_down(s, off); s2 += __shfl_down(s2, off); }
  __shared__ float ss[4], sq[4];
  if ((tid & 63) == 0) { ss[tid >> 6] = s; sq[tid >> 6] = s2; }
  __syncthreads();
  float mean = (ss[0]+ss[1]+ss[2]+ss[3]) * (1.0f/DM);
  float var  = (sq[0]+sq[1]+sq[2]+sq[3]) * (1.0f/DM) - mean*mean;
  float rs = rsqrtf(var + 1e-5f);
  float4 wv = ((const float4*)w)[tid];
  float4 bv = ((const float4*)b)[tid];
  ushort4 o;
  o.x = f2bf((v.x-mean)*rs*wv.x + bv.x);
  o.y = f2bf((v.y-mean)*rs*wv.y + bv.y);
  o.z = f2bf((v.z-mean)*rs*wv.z + bv.z);
  o.w = f2bf((v.w-mean)*rs*wv.w + bv.w);
  ((ushort4*)(out + (size_t)row * DM))[tid] = o;
}

// ---------------- f32 -> bf16 cast (vectorized) ----------------
__global__ __launch_bounds__(256) void castk(const float* __restrict__ in,
    unsigned short* __restrict__ out, int n4)
{
  int i = blockIdx.x * 256 + threadIdx.x;
  int stride = gridDim.x * 256;
  for (; i < n4; i += stride) {
    float4 v = ((const float4*)in)[i];
    ushort4 o;
    o.x = f2bf(v.x); o.y = f2bf(v.y); o.z = f2bf(v.z); o.w = f2bf(v.w);
    ((ushort4*)out)[i] = o;
  }
}

// ---------------- bf16 MFMA GEMM: C = A(M,K) @ B(N,K)^T + bias ----------------
// EPI: 0 = plain, 1 = softplus, 2 = + residual
template<int EPI>
__global__ __launch_bounds__(256) void gemm_bt(
    const unsigned short* __restrict__ A, const unsigned short* __restrict__ Bw,
    const float* __restrict__ bias, const float* __restrict__ resid,
    float* __restrict__ C, int N, int K)
{
  __shared__ unsigned short As[128*32];
  __shared__ unsigned short Bs[128*32];
  const int tid  = threadIdx.x;
  const int lane = tid & 63;
  const int w    = tid >> 6;
  const int m0 = blockIdx.y * 128;
  const int n0 = blockIdx.x * 128;
  const int wm = w >> 1, wn = w & 1;

  const int segA = w * 2;            // this wave stages segs segA, segA+1 (16 rows each)
  const int rsub = lane >> 2;        // row within segment
  const int kc   = (lane & 3) * 8;   // k element offset (16B granules)

  const int r16 = lane & 15;
  const int kg  = lane >> 4;

  f32x4 acc[4][4] = {};

  for (int kt = 0; kt < K; kt += 32) {
    const unsigned short* ga0 = A  + (size_t)(m0 + segA*16 + rsub) * K + kt + kc;
    load_lds16(ga0,               &As[ segA   *512]);
    load_lds16(ga0 + (size_t)16*K, &As[(segA+1)*512]);
    const unsigned short* gb0 = Bw + (size_t)(n0 + segA*16 + rsub) * K + kt + kc;
    load_lds16(gb0,               &Bs[ segA   *512]);
    load_lds16(gb0 + (size_t)16*K, &Bs[(segA+1)*512]);
    __syncthreads();   // drains vmcnt -> staged data visible

    bf16x8 av[4], bv[4];
    #pragma unroll
    for (int i = 0; i < 4; ++i) {
      int row = wm*64 + i*16 + r16;
      av[i] = *(const bf16x8*)((const char*)As + row*64 + kg*16);
    }
    #pragma unroll
    for (int j = 0; j < 4; ++j) {
      int row = wn*64 + j*16 + r16;
      bv[j] = *(const bf16x8*)((const char*)Bs + row*64 + kg*16);
    }
    #pragma unroll
    for (int i = 0; i < 4; ++i)
      #pragma unroll
      for (int j = 0; j < 4; ++j)
        acc[i][j] = __builtin_amdgcn_mfma_f32_16x16x32_bf16(av[i], bv[j], acc[i][j], 0, 0, 0);
    __syncthreads();   // done reading before next overwrite
  }

  #pragma unroll
  for (int i = 0; i < 4; ++i) {
    int rbase = m0 + wm*64 + i*16 + kg*4;
    #pragma unroll
    for (int j = 0; j < 4; ++j) {
      int col = n0 + wn*64 + j*16 + r16;
      float bcol = bias[col];
      #pragma unroll
      for (int r = 0; r < 4; ++r) {
        int row = rbase + r;
        float v = acc[i][j][r] + bcol;
        if (EPI == 1) v = (v > 20.f) ? v : log1pf(__expf(v));
        if (EPI == 2) v += resid[(size_t)row * N + col];
        C[(size_t)row * N + col] = v;
      }
    }
  }
}

// ---------------- depthwise causal conv1d + SiLU ----------------
__global__ __launch_bounds__(256) void conv_silu(const float* __restrict__ xz,
    const float* __restrict__ cw, const float* __restrict__ cb,
    float* __restrict__ u, unsigned short* __restrict__ u_bf)
{
  int idx = blockIdx.x * 256 + threadIdx.x;   // 0 .. MROWS*DI-1
  int d = idx & (DI-1);
  int m = idx >> 11;
  int l = m & (LSEQ-1);
  const float* col = xz + (size_t)m * (2*DI) + d;   // xz row stride 4096, xc = first half
  float acc = cb[d];
  float w0 = cw[d*4+0], w1 = cw[d*4+1], w2 = cw[d*4+2], w3 = cw[d*4+3];
  acc += w3 * col[0];
  if (l >= 1) acc += w2 * col[-(2*DI)];
  if (l >= 2) acc += w1 * col[-2*(2*DI)];
  if (l >= 3) acc += w0 * col[-3*(2*DI)];
  float s = acc / (1.f + __expf(-acc));
  u[idx]    = s;
  u_bf[idx] = f2bf(s);
}

// ---------------- x_proj: xdb(M,32) = u(M,2048) @ W(32,2048)^T + b ----------------
__global__ __launch_bounds__(256) void xproj_k(const float* __restrict__ u,
    const float* __restrict__ W, const float* __restrict__ bias,
    float* __restrict__ xdb)
{
  __shared__ float su[DI];
  __shared__ float red[256];
  int m = blockIdx.x, tid = threadIdx.x;
  const float4* ur = (const float4*)(u + (size_t)m * DI);
  ((float4*)su)[tid]       = ur[tid];
  ((float4*)su)[tid + 256] = ur[tid + 256];
  __syncthreads();
  int n = tid & 31, c = tid >> 5;   // c in 0..7
  const float* wrow = W + n*DI + c*256;
  const float* sp   = su + c*256;
  float p = 0.f;
  #pragma unroll 4
  for (int i = 0; i < 256; ++i) p += sp[i] * wrow[i];
  red[tid] = p;
  __syncthreads();
  if (tid < 32) {
    float sacc = bias[tid];
    #pragma unroll
    for (int cc = 0; cc < 8; ++cc) sacc += red[cc*32 + tid];
    xdb[m*32 + tid] = sacc;
  }
}

// ---------------- selective scan (16 lanes = 16 states per channel) ----------------
__global__ __launch_bounds__(256) void scan_k(const float* __restrict__ delta,
    const float* __restrict__ u, const float* __restrict__ xdb,
    const float* __restrict__ A_log, const float* __restrict__ Dp,
    const float* __restrict__ xz, unsigned short* __restrict__ y_bf)
{
  int tid = threadIdx.x;
  int ch  = blockIdx.x * 16 + (tid >> 4);   // 0..4095 = b*DI + d
  int s   = tid & 15;
  int b   = ch >> 11, d = ch & (DI-1);
  float Ads = -__expf(A_log[d*16 + s]);
  float Dd  = Dp[d];
  float h = 0.f;
  size_t lbase = (size_t)b * LSEQ;
  for (int l0 = 0; l0 < LSEQ; l0 += 8) {
    float y8[8];
    #pragma unroll
    for (int t = 0; t < 8; ++t) {
      size_t row = lbase + l0 + t;
      float dl = delta[row*DI + d];
      float uu = u[row*DI + d];
      float Bv = xdb[row*32 + s];
      float Cv = xdb[row*32 + 16 + s];
      float dA = __expf(dl * Ads);
      h = fmaf(dA, h, dl * uu * Bv);
      y8[t] = h * Cv;
    }
    #pragma unroll
    for (int t = 0; t < 8; ++t) {
      float p = y8[t];
      p += __shfl_xor(p, 8);
      p += __shfl_xor(p, 4);
      p += __shfl_xor(p, 2);
      p += __shfl_xor(p, 1);
      y8[t] = p;
    }
    if (s == 0) {
      #pragma unroll
      for (int t = 0; t < 8; ++t) {
        size_t row = lbase + l0 + t;
        float uu = u[row*DI + d];
        float zz = xz[row*(2*DI) + DI + d];
        float yv = y8[t] + uu * Dd;
        yv *= zz / (1.f + __expf(-zz));
        y_bf[row*DI + d] = f2bf(yv);
      }
    }
  }
}

extern "C" void kernel_launch(void* const* d_in, const int* in_sizes, int n_in,
                              void* d_out, int out_size, void* d_ws, size_t ws_size,
                              hipStream_t stream)
{
  (void)in_sizes; (void)n_in; (void)out_size;
  const float* x      = (const float*)d_in[0];
  const float* norm_w = (const float*)d_in[1];
  const float* norm_b = (const float*)d_in[2];
  const float* in_w   = (const float*)d_in[3];
  const float* in_b   = (const float*)d_in[4];
  const float* conv_w = (const float*)d_in[5];
  const float* conv_b = (const float*)d_in[6];
  const float* xp_w   = (const float*)d_in[7];
  const float* xp_b   = (const float*)d_in[8];
  const float* dt_w   = (const float*)d_in[9];
  const float* dt_b   = (const float*)d_in[10];
  const float* A_log  = (const float*)d_in[11];
  const float* D_par  = (const float*)d_in[12];
  const float* out_w  = (const float*)d_in[13];
  const float* out_b  = (const float*)d_in[14];
  float* out = (float*)d_out;

  char* p = (char*)d_ws;
  unsigned short* xn_bf = (unsigned short*)p;  p += 2048ull*1024*2;
  unsigned short* w_in  = (unsigned short*)p;  p += 4096ull*1024*2;
  unsigned short* w_dt  = (unsigned short*)p;  p += 2048ull*2048*2;
  unsigned short* w_out = (unsigned short*)p;  p += 1024ull*2048*2;
  float*          xz    = (float*)p;           p += 2048ull*4096*4;
  float*          u_f   = (float*)p;           p += 2048ull*2048*4;
  unsigned short* u_bf  = (unsigned short*)p;  p += 2048ull*2048*2;
  float*          xdb   = (float*)p;           p += 2048ull*32*4;
  float*          delta = (float*)p;           p += 2048ull*2048*4;
  unsigned short* y_bf  = (unsigned short*)p;  p += 2048ull*2048*2;
  if ((size_t)(p - (char*)d_ws) > ws_size) return;  // ws too small: fail visibly

  ln_cast<<<MROWS, 256, 0, stream>>>(x, norm_w, norm_b, xn_bf);
  castk<<<2048, 256, 0, stream>>>(in_w,  w_in,  4096*1024/4);
  castk<<<2048, 256, 0, stream>>>(dt_w,  w_dt,  2048*2048/4);
  castk<<<1024, 256, 0, stream>>>(out_w, w_out, 1024*2048/4);

  gemm_bt<0><<<dim3(4096/128, MROWS/128), 256, 0, stream>>>(xn_bf, w_in, in_b, nullptr, xz, 4096, 1024);
  conv_silu<<<(MROWS*DI)/256, 256, 0, stream>>>(xz, conv_w, conv_b, u_f, u_bf);
  xproj_k<<<MROWS, 256, 0, stream>>>(u_f, xp_w, xp_b, xdb);
  gemm_bt<1><<<dim3(2048/128, MROWS/128), 256, 0, stream>>>(u_bf, w_dt, dt_b, nullptr, delta, 2048, 2048);
  scan_k<<<(BSZ*DI)/16, 256, 0, stream>>>(delta, u_f, xdb, A_log, D_par, xz, y_bf);
  gemm_bt<2><<<dim3(1024/128, MROWS/128), 256, 0, stream>>>(y_bf, w_out, out_b, x, out, 1024, 2048);
}

// Round 5
// 353.354 us; speedup vs baseline: 1.2567x; 1.2567x over previous
//
#include <hip/hip_runtime.h>

#define DM   1024
#define DI   2048
#define LSEQ 1024
#define BSZ  2
#define MROWS (BSZ*LSEQ)   // 2048
#define NCH   (BSZ*DI)     // 4096 channels
#define SCHUNK 32          // chunks per sequence
#define STEPS  32          // steps per chunk (SCHUNK*STEPS == LSEQ)
#define PLANE  (NCH*16)    // per-chunk aggregate plane (65536)

typedef __attribute__((ext_vector_type(4))) float  f32x4;
typedef __attribute__((ext_vector_type(8))) __bf16 bf16x8;

__device__ __forceinline__ unsigned short f2bf(float f) {
  union { float f; unsigned int u; } v; v.f = f;
  unsigned int u = v.u;
  unsigned int r = (u + 0x7fffu + ((u >> 16) & 1u)) >> 16;  // RNE
  return (unsigned short)r;
}

__device__ __forceinline__ void load_lds16(const void* g, void* l) {
  __builtin_amdgcn_global_load_lds((const __attribute__((address_space(1))) void*)g,
                                   (__attribute__((address_space(3))) void*)l, 16, 0, 0);
}

// ---------------- LayerNorm + cast to bf16 ----------------
__global__ __launch_bounds__(256) void ln_cast(const float* __restrict__ x,
    const float* __restrict__ w, const float* __restrict__ b,
    unsigned short* __restrict__ out)
{
  int row = blockIdx.x, tid = threadIdx.x;
  const float4* xr = (const float4*)(x + (size_t)row * DM);
  float4 v = xr[tid];
  float s  = v.x + v.y + v.z + v.w;
  float s2 = v.x*v.x + v.y*v.y + v.z*v.z + v.w*v.w;
  #pragma unroll
  for (int off = 32; off > 0; off >>= 1) { s += __shfl_down(s, off); s2 += __shfl_down(s2, off); }
  __shared__ float ss[4], sq[4];
  if ((tid & 63) == 0) { ss[tid >> 6] = s; sq[tid >> 6] = s2; }
  __syncthreads();
  float mean = (ss[0]+ss[1]+ss[2]+ss[3]) * (1.0f/DM);
  float var  = (sq[0]+sq[1]+sq[2]+sq[3]) * (1.0f/DM) - mean*mean;
  float rs = rsqrtf(var + 1e-5f);
  float4 wv = ((const float4*)w)[tid];
  float4 bv = ((const float4*)b)[tid];
  ushort4 o;
  o.x = f2bf((v.x-mean)*rs*wv.x + bv.x);
  o.y = f2bf((v.y-mean)*rs*wv.y + bv.y);
  o.z = f2bf((v.z-mean)*rs*wv.z + bv.z);
  o.w = f2bf((v.w-mean)*rs*wv.w + bv.w);
  ((ushort4*)(out + (size_t)row * DM))[tid] = o;
}

// ---------------- f32 -> bf16 cast (vectorized) ----------------
__global__ __launch_bounds__(256) void castk(const float* __restrict__ in,
    unsigned short* __restrict__ out, int n4)
{
  int i = blockIdx.x * 256 + threadIdx.x;
  int stride = gridDim.x * 256;
  for (; i < n4; i += stride) {
    float4 v = ((const float4*)in)[i];
    ushort4 o;
    o.x = f2bf(v.x); o.y = f2bf(v.y); o.z = f2bf(v.z); o.w = f2bf(v.w);
    ((ushort4*)out)[i] = o;
  }
}

// ---------------- bf16 MFMA GEMM: C = A(M,K) @ B(N,K)^T + bias ----------------
// EPI: 0 = plain, 1 = softplus, 2 = + residual
template<int EPI>
__global__ __launch_bounds__(256) void gemm_bt(
    const unsigned short* __restrict__ A, const unsigned short* __restrict__ Bw,
    const float* __restrict__ bias, const float* __restrict__ resid,
    float* __restrict__ C, int N, int K)
{
  __shared__ unsigned short As[128*32];
  __shared__ unsigned short Bs[128*32];
  const int tid  = threadIdx.x;
  const int lane = tid & 63;
  const int w    = tid >> 6;
  const int m0 = blockIdx.y * 128;
  const int n0 = blockIdx.x * 128;
  const int wm = w >> 1, wn = w & 1;

  const int segA = w * 2;            // this wave stages segs segA, segA+1 (16 rows each)
  const int rsub = lane >> 2;        // row within segment
  const int kc   = (lane & 3) * 8;   // k element offset (16B granules)

  const int r16 = lane & 15;
  const int kg  = lane >> 4;

  f32x4 acc[4][4] = {};

  for (int kt = 0; kt < K; kt += 32) {
    const unsigned short* ga0 = A  + (size_t)(m0 + segA*16 + rsub) * K + kt + kc;
    load_lds16(ga0,               &As[ segA   *512]);
    load_lds16(ga0 + (size_t)16*K, &As[(segA+1)*512]);
    const unsigned short* gb0 = Bw + (size_t)(n0 + segA*16 + rsub) * K + kt + kc;
    load_lds16(gb0,               &Bs[ segA   *512]);
    load_lds16(gb0 + (size_t)16*K, &Bs[(segA+1)*512]);
    __syncthreads();   // drains vmcnt -> staged data visible

    bf16x8 av[4], bv[4];
    #pragma unroll
    for (int i = 0; i < 4; ++i) {
      int row = wm*64 + i*16 + r16;
      av[i] = *(const bf16x8*)((const char*)As + row*64 + kg*16);
    }
    #pragma unroll
    for (int j = 0; j < 4; ++j) {
      int row = wn*64 + j*16 + r16;
      bv[j] = *(const bf16x8*)((const char*)Bs + row*64 + kg*16);
    }
    #pragma unroll
    for (int i = 0; i < 4; ++i)
      #pragma unroll
      for (int j = 0; j < 4; ++j)
        acc[i][j] = __builtin_amdgcn_mfma_f32_16x16x32_bf16(av[i], bv[j], acc[i][j], 0, 0, 0);
    __syncthreads();   // done reading before next overwrite
  }

  #pragma unroll
  for (int i = 0; i < 4; ++i) {
    int rbase = m0 + wm*64 + i*16 + kg*4;
    #pragma unroll
    for (int j = 0; j < 4; ++j) {
      int col = n0 + wn*64 + j*16 + r16;
      float bcol = bias[col];
      #pragma unroll
      for (int r = 0; r < 4; ++r) {
        int row = rbase + r;
        float v = acc[i][j][r] + bcol;
        if (EPI == 1) v = (v > 20.f) ? v : log1pf(__expf(v));
        if (EPI == 2) v += resid[(size_t)row * N + col];
        C[(size_t)row * N + col] = v;
      }
    }
  }
}

// ---------------- depthwise causal conv1d + SiLU ----------------
__global__ __launch_bounds__(256) void conv_silu(const float* __restrict__ xz,
    const float* __restrict__ cw, const float* __restrict__ cb,
    float* __restrict__ u, unsigned short* __restrict__ u_bf)
{
  int idx = blockIdx.x * 256 + threadIdx.x;   // 0 .. MROWS*DI-1
  int d = idx & (DI-1);
  int m = idx >> 11;
  int l = m & (LSEQ-1);
  const float* col = xz + (size_t)m * (2*DI) + d;   // xz row stride 4096, xc = first half
  float acc = cb[d];
  float w0 = cw[d*4+0], w1 = cw[d*4+1], w2 = cw[d*4+2], w3 = cw[d*4+3];
  acc += w3 * col[0];
  if (l >= 1) acc += w2 * col[-(2*DI)];
  if (l >= 2) acc += w1 * col[-2*(2*DI)];
  if (l >= 3) acc += w0 * col[-3*(2*DI)];
  float s = acc / (1.f + __expf(-acc));
  u[idx]    = s;
  u_bf[idx] = f2bf(s);
}

// ---------------- x_proj: xdb(M,32) = u(M,2048) @ W(32,2048)^T + b ----------------
__global__ __launch_bounds__(256) void xproj_k(const float* __restrict__ u,
    const float* __restrict__ W, const float* __restrict__ bias,
    float* __restrict__ xdb)
{
  __shared__ float su[DI];
  __shared__ float red[256];
  int m = blockIdx.x, tid = threadIdx.x;
  const float4* ur = (const float4*)(u + (size_t)m * DI);
  ((float4*)su)[tid]       = ur[tid];
  ((float4*)su)[tid + 256] = ur[tid + 256];
  __syncthreads();
  int n = tid & 31, c = tid >> 5;   // c in 0..7
  const float* wrow = W + n*DI + c*256;
  const float* sp   = su + c*256;
  float p = 0.f;
  #pragma unroll 4
  for (int i = 0; i < 256; ++i) p += sp[i] * wrow[i];
  red[tid] = p;
  __syncthreads();
  if (tid < 32) {
    float sacc = bias[tid];
    #pragma unroll
    for (int cc = 0; cc < 8; ++cc) sacc += red[cc*32 + tid];
    xdb[m*32 + tid] = sacc;
  }
}

// ---------------- chunked selective scan ----------------
// pass 1: per-(ch,s,chunk) aggregate (a = prod dA, b = folded dBu)
__global__ __launch_bounds__(256) void scan_p1(const float* __restrict__ delta,
    const float* __restrict__ u, const float* __restrict__ xdb,
    const float* __restrict__ A_log, float* __restrict__ agg_a, float* __restrict__ agg_b)
{
  int tid = threadIdx.x;
  int s = tid & 15, g = tid >> 4;
  int ch = blockIdx.x * 16 + g;           // 0..4095
  int c  = blockIdx.y;                    // chunk
  int b = ch >> 11, d = ch & (DI-1);
  float Ads = -__expf(A_log[d*16 + s]);
  size_t row0 = (size_t)b * LSEQ + (size_t)c * STEPS;
  const float* dp = delta + row0*DI + d;
  const float* up = u     + row0*DI + d;
  const float* xp = xdb   + row0*32 + s;
  float a = 1.f, bb = 0.f;
  #pragma unroll 8
  for (int t = 0; t < STEPS; ++t) {
    float dl = dp[(size_t)t*DI];
    float uu = up[(size_t)t*DI];
    float Bv = xp[t*32];
    float dA = __expf(dl * Ads);
    bb = fmaf(dA, bb, dl * uu * Bv);
    a *= dA;
  }
  int idx = c*PLANE + ch*16 + s;
  agg_a[idx] = a;
  agg_b[idx] = bb;
}

// pass 2: sequential scan over chunk aggregates -> h at each chunk start
__global__ __launch_bounds__(256) void scan_p2(const float* __restrict__ agg_a,
    const float* __restrict__ agg_b, float* __restrict__ hinit)
{
  int idx = blockIdx.x * 256 + threadIdx.x;   // 0..PLANE-1
  float h = 0.f;
  #pragma unroll
  for (int c = 0; c < SCHUNK; ++c) {
    hinit[c*PLANE + idx] = h;
    h = fmaf(agg_a[c*PLANE + idx], h, agg_b[c*PLANE + idx]);
  }
}

// pass 3: replay within chunk from hinit, reduce over 16 states, gated epilogue
__global__ __launch_bounds__(256) void scan_p3(const float* __restrict__ delta,
    const float* __restrict__ u, const float* __restrict__ xdb,
    const float* __restrict__ A_log, const float* __restrict__ Dp,
    const float* __restrict__ xz, const float* __restrict__ hinit,
    unsigned short* __restrict__ y_bf)
{
  int tid = threadIdx.x;
  int s = tid & 15, g = tid >> 4;
  int ch = blockIdx.x * 16 + g;
  int c  = blockIdx.y;
  int b = ch >> 11, d = ch & (DI-1);
  float Ads = -__expf(A_log[d*16 + s]);
  float Dd  = Dp[d];
  float h = hinit[c*PLANE + ch*16 + s];
  size_t row0 = (size_t)b * LSEQ + (size_t)c * STEPS;
  for (int t0 = 0; t0 < STEPS; t0 += 8) {
    float y8[8];
    #pragma unroll
    for (int t = 0; t < 8; ++t) {
      size_t row = row0 + t0 + t;
      float dl = delta[row*DI + d];
      float uu = u[row*DI + d];
      float Bv = xdb[row*32 + s];
      float Cv = xdb[row*32 + 16 + s];
      float dA = __expf(dl * Ads);
      h = fmaf(dA, h, dl * uu * Bv);
      y8[t] = h * Cv;
    }
    #pragma unroll
    for (int t = 0; t < 8; ++t) {
      float p = y8[t];
      p += __shfl_xor(p, 8);
      p += __shfl_xor(p, 4);
      p += __shfl_xor(p, 2);
      p += __shfl_xor(p, 1);
      y8[t] = p;
    }
    if (s == 0) {
      #pragma unroll
      for (int t = 0; t < 8; ++t) {
        size_t row = row0 + t0 + t;
        float uu = u[row*DI + d];
        float zz = xz[row*(2*DI) + DI + d];
        float yv = y8[t] + uu * Dd;
        yv *= zz / (1.f + __expf(-zz));
        y_bf[row*DI + d] = f2bf(yv);
      }
    }
  }
}

extern "C" void kernel_launch(void* const* d_in, const int* in_sizes, int n_in,
                              void* d_out, int out_size, void* d_ws, size_t ws_size,
                              hipStream_t stream)
{
  (void)in_sizes; (void)n_in; (void)out_size;
  const float* x      = (const float*)d_in[0];
  const float* norm_w = (const float*)d_in[1];
  const float* norm_b = (const float*)d_in[2];
  const float* in_w   = (const float*)d_in[3];
  const float* in_b   = (const float*)d_in[4];
  const float* conv_w = (const float*)d_in[5];
  const float* conv_b = (const float*)d_in[6];
  const float* xp_w   = (const float*)d_in[7];
  const float* xp_b   = (const float*)d_in[8];
  const float* dt_w   = (const float*)d_in[9];
  const float* dt_b   = (const float*)d_in[10];
  const float* A_log  = (const float*)d_in[11];
  const float* D_par  = (const float*)d_in[12];
  const float* out_w  = (const float*)d_in[13];
  const float* out_b  = (const float*)d_in[14];
  float* out = (float*)d_out;

  char* p = (char*)d_ws;
  unsigned short* xn_bf = (unsigned short*)p;  p += 2048ull*1024*2;
  unsigned short* w_in  = (unsigned short*)p;  p += 4096ull*1024*2;   // 8 MB
  unsigned short* w_dt  = (unsigned short*)p;  p += 2048ull*2048*2;   // 8 MB
  unsigned short* w_out = (unsigned short*)p;  p += 1024ull*2048*2;
  float*          xz    = (float*)p;           p += 2048ull*4096*4;
  float*          u_f   = (float*)p;           p += 2048ull*2048*4;
  unsigned short* u_bf  = (unsigned short*)p;  p += 2048ull*2048*2;   // 8 MB
  float*          xdb   = (float*)p;           p += 2048ull*32*4;
  float*          delta = (float*)p;           p += 2048ull*2048*4;
  unsigned short* y_bf  = (unsigned short*)p;  p += 2048ull*2048*2;
  if ((size_t)(p - (char*)d_ws) > ws_size) return;  // ws too small: fail visibly

  // scan scratch overlays regions that are dead by scan time:
  //   w_in  (dead after gemm<0>)  -> agg_a (8 MB)
  //   w_dt  (dead after gemm<1>)  -> agg_b (8 MB)
  //   u_bf  (dead after gemm<1>)  -> hinit (8 MB)
  float* agg_a = (float*)w_in;
  float* agg_b = (float*)w_dt;
  float* hinit = (float*)u_bf;

  ln_cast<<<MROWS, 256, 0, stream>>>(x, norm_w, norm_b, xn_bf);
  castk<<<2048, 256, 0, stream>>>(in_w,  w_in,  4096*1024/4);
  castk<<<2048, 256, 0, stream>>>(dt_w,  w_dt,  2048*2048/4);
  castk<<<1024, 256, 0, stream>>>(out_w, w_out, 1024*2048/4);

  gemm_bt<0><<<dim3(4096/128, MROWS/128), 256, 0, stream>>>(xn_bf, w_in, in_b, nullptr, xz, 4096, 1024);
  conv_silu<<<(MROWS*DI)/256, 256, 0, stream>>>(xz, conv_w, conv_b, u_f, u_bf);
  xproj_k<<<MROWS, 256, 0, stream>>>(u_f, xp_w, xp_b, xdb);
  gemm_bt<1><<<dim3(2048/128, MROWS/128), 256, 0, stream>>>(u_bf, w_dt, dt_b, nullptr, delta, 2048, 2048);

  scan_p1<<<dim3(NCH/16, SCHUNK), 256, 0, stream>>>(delta, u_f, xdb, A_log, agg_a, agg_b);
  scan_p2<<<PLANE/256, 256, 0, stream>>>(agg_a, agg_b, hinit);
  scan_p3<<<dim3(NCH/16, SCHUNK), 256, 0, stream>>>(delta, u_f, xdb, A_log, D_par, xz, hinit, y_bf);

  gemm_bt<2><<<dim3(1024/128, MROWS/128), 256, 0, stream>>>(y_bf, w_out, out_b, x, out, 1024, 2048);
}

// Round 8
// 298.347 us; speedup vs baseline: 1.4884x; 1.1844x over previous
//
#include <hip/hip_runtime.h>

#define DM   1024
#define DI   2048
#define LSEQ 1024
#define BSZ  2
#define MROWS (BSZ*LSEQ)   // 2048
#define NCH   (BSZ*DI)     // 4096 channels
#define SCHUNK 32          // chunks per sequence
#define STEPS  32          // steps per chunk (SCHUNK*STEPS == LSEQ)
#define PLANE  (NCH*16)    // per-chunk aggregate plane (65536)

typedef __attribute__((ext_vector_type(4))) float  f32x4;
typedef __attribute__((ext_vector_type(8))) __bf16 bf16x8;

__device__ __forceinline__ unsigned short f2bf(float f) {
  union { float f; unsigned int u; } v; v.f = f;
  unsigned int u = v.u;
  unsigned int r = (u + 0x7fffu + ((u >> 16) & 1u)) >> 16;  // RNE
  return (unsigned short)r;
}

__device__ __forceinline__ void load_lds16(const void* g, void* l) {
  __builtin_amdgcn_global_load_lds((const __attribute__((address_space(1))) void*)g,
                                   (__attribute__((address_space(3))) void*)l, 16, 0, 0);
}

// ---------------- LayerNorm + cast to bf16 ----------------
__global__ __launch_bounds__(256) void ln_cast(const float* __restrict__ x,
    const float* __restrict__ w, const float* __restrict__ b,
    unsigned short* __restrict__ out)
{
  int row = blockIdx.x, tid = threadIdx.x;
  const float4* xr = (const float4*)(x + (size_t)row * DM);
  float4 v = xr[tid];
  float s  = v.x + v.y + v.z + v.w;
  float s2 = v.x*v.x + v.y*v.y + v.z*v.z + v.w*v.w;
  #pragma unroll
  for (int off = 32; off > 0; off >>= 1) { s += __shfl_down(s, off); s2 += __shfl_down(s2, off); }
  __shared__ float ss[4], sq[4];
  if ((tid & 63) == 0) { ss[tid >> 6] = s; sq[tid >> 6] = s2; }
  __syncthreads();
  float mean = (ss[0]+ss[1]+ss[2]+ss[3]) * (1.0f/DM);
  float var  = (sq[0]+sq[1]+sq[2]+sq[3]) * (1.0f/DM) - mean*mean;
  float rs = rsqrtf(var + 1e-5f);
  float4 wv = ((const float4*)w)[tid];
  float4 bv = ((const float4*)b)[tid];
  ushort4 o;
  o.x = f2bf((v.x-mean)*rs*wv.x + bv.x);
  o.y = f2bf((v.y-mean)*rs*wv.y + bv.y);
  o.z = f2bf((v.z-mean)*rs*wv.z + bv.z);
  o.w = f2bf((v.w-mean)*rs*wv.w + bv.w);
  ((ushort4*)(out + (size_t)row * DM))[tid] = o;
}

// ---------------- f32 -> bf16 cast (vectorized) ----------------
__global__ __launch_bounds__(256) void castk(const float* __restrict__ in,
    unsigned short* __restrict__ out, int n4)
{
  int i = blockIdx.x * 256 + threadIdx.x;
  int stride = gridDim.x * 256;
  for (; i < n4; i += stride) {
    float4 v = ((const float4*)in)[i];
    ushort4 o;
    o.x = f2bf(v.x); o.y = f2bf(v.y); o.z = f2bf(v.z); o.w = f2bf(v.w);
    ((ushort4*)out)[i] = o;
  }
}

// ---------------- bf16 MFMA GEMM: C = A(M,K) @ B(N,K)^T + bias ----------------
// EPI: 0 = plain, 1 = softplus, 2 = + residual
template<int EPI>
__global__ __launch_bounds__(256) void gemm_bt(
    const unsigned short* __restrict__ A, const unsigned short* __restrict__ Bw,
    const float* __restrict__ bias, const float* __restrict__ resid,
    float* __restrict__ C, int N, int K)
{
  __shared__ unsigned short As[128*32];
  __shared__ unsigned short Bs[128*32];
  const int tid  = threadIdx.x;
  const int lane = tid & 63;
  const int w    = tid >> 6;
  const int m0 = blockIdx.y * 128;
  const int n0 = blockIdx.x * 128;
  const int wm = w >> 1, wn = w & 1;

  const int segA = w * 2;            // this wave stages segs segA, segA+1 (16 rows each)
  const int rsub = lane >> 2;        // row within segment
  const int kc   = (lane & 3) * 8;   // k element offset (16B granules)

  const int r16 = lane & 15;
  const int kg  = lane >> 4;

  f32x4 acc[4][4] = {};

  for (int kt = 0; kt < K; kt += 32) {
    const unsigned short* ga0 = A  + (size_t)(m0 + segA*16 + rsub) * K + kt + kc;
    load_lds16(ga0,               &As[ segA   *512]);
    load_lds16(ga0 + (size_t)16*K, &As[(segA+1)*512]);
    const unsigned short* gb0 = Bw + (size_t)(n0 + segA*16 + rsub) * K + kt + kc;
    load_lds16(gb0,               &Bs[ segA   *512]);
    load_lds16(gb0 + (size_t)16*K, &Bs[(segA+1)*512]);
    __syncthreads();   // drains vmcnt -> staged data visible

    bf16x8 av[4], bv[4];
    #pragma unroll
    for (int i = 0; i < 4; ++i) {
      int row = wm*64 + i*16 + r16;
      av[i] = *(const bf16x8*)((const char*)As + row*64 + kg*16);
    }
    #pragma unroll
    for (int j = 0; j < 4; ++j) {
      int row = wn*64 + j*16 + r16;
      bv[j] = *(const bf16x8*)((const char*)Bs + row*64 + kg*16);
    }
    #pragma unroll
    for (int i = 0; i < 4; ++i)
      #pragma unroll
      for (int j = 0; j < 4; ++j)
        acc[i][j] = __builtin_amdgcn_mfma_f32_16x16x32_bf16(av[i], bv[j], acc[i][j], 0, 0, 0);
    __syncthreads();   // done reading before next overwrite
  }

  #pragma unroll
  for (int i = 0; i < 4; ++i) {
    int rbase = m0 + wm*64 + i*16 + kg*4;
    #pragma unroll
    for (int j = 0; j < 4; ++j) {
      int col = n0 + wn*64 + j*16 + r16;
      float bcol = bias[col];
      #pragma unroll
      for (int r = 0; r < 4; ++r) {
        int row = rbase + r;
        float v = acc[i][j][r] + bcol;
        if (EPI == 1) v = (v > 20.f) ? v : log1pf(__expf(v));
        if (EPI == 2) v += resid[(size_t)row * N + col];
        C[(size_t)row * N + col] = v;
      }
    }
  }
}

// ---------------- depthwise causal conv1d + SiLU ----------------
__global__ __launch_bounds__(256) void conv_silu(const float* __restrict__ xz,
    const float* __restrict__ cw, const float* __restrict__ cb,
    float* __restrict__ u, unsigned short* __restrict__ u_bf)
{
  int idx = blockIdx.x * 256 + threadIdx.x;   // 0 .. MROWS*DI-1
  int d = idx & (DI-1);
  int m = idx >> 11;
  int l = m & (LSEQ-1);
  const float* col = xz + (size_t)m * (2*DI) + d;   // xz row stride 4096, xc = first half
  float acc = cb[d];
  float w0 = cw[d*4+0], w1 = cw[d*4+1], w2 = cw[d*4+2], w3 = cw[d*4+3];
  acc += w3 * col[0];
  if (l >= 1) acc += w2 * col[-(2*DI)];
  if (l >= 2) acc += w1 * col[-2*(2*DI)];
  if (l >= 3) acc += w0 * col[-3*(2*DI)];
  float s = acc / (1.f + __expf(-acc));
  u[idx]    = s;
  u_bf[idx] = f2bf(s);
}

// ---------------- x_proj via MFMA: xdb(M,32) = u_bf(M,2048) @ wx(32,2048)^T + b ----
// one wave per 16 rows; W (128 KB bf16) is L1/L2-resident
__global__ __launch_bounds__(64) void xproj_mfma(const unsigned short* __restrict__ u_bf,
    const unsigned short* __restrict__ wx, const float* __restrict__ bias,
    float* __restrict__ xdb)
{
  int lane = threadIdx.x;            // 0..63
  int m0 = blockIdx.x * 16;
  int r16 = lane & 15, kg = lane >> 4;
  f32x4 acc0 = {}, acc1 = {};
  const unsigned short* ap  = u_bf + (size_t)(m0 + r16) * DI + kg*8;
  const unsigned short* b0p = wx   + (size_t)r16        * DI + kg*8;
  const unsigned short* b1p = wx   + (size_t)(16 + r16) * DI + kg*8;
  #pragma unroll 4
  for (int kt = 0; kt < DI; kt += 32) {
    bf16x8 a  = *(const bf16x8*)(ap  + kt);
    bf16x8 b0 = *(const bf16x8*)(b0p + kt);
    bf16x8 b1 = *(const bf16x8*)(b1p + kt);
    acc0 = __builtin_amdgcn_mfma_f32_16x16x32_bf16(a, b0, acc0, 0, 0, 0);
    acc1 = __builtin_amdgcn_mfma_f32_16x16x32_bf16(a, b1, acc1, 0, 0, 0);
  }
  #pragma unroll
  for (int r = 0; r < 4; ++r) {
    int row = m0 + kg*4 + r;
    xdb[row*32 + r16]      = acc0[r] + bias[r16];
    xdb[row*32 + 16 + r16] = acc1[r] + bias[16 + r16];
  }
}

// ---------------- chunked selective scan ----------------
// pass 1: per-(ch,s,chunk) aggregate (a = prod dA, b = folded dBu)
__global__ __launch_bounds__(256) void scan_p1(const float* __restrict__ delta,
    const float* __restrict__ u, const float* __restrict__ xdb,
    const float* __restrict__ A_log, float* __restrict__ agg_a, float* __restrict__ agg_b)
{
  int tid = threadIdx.x;
  int s = tid & 15, g = tid >> 4;
  int ch = blockIdx.x * 16 + g;           // 0..4095
  int c  = blockIdx.y;                    // chunk
  int b = ch >> 11, d = ch & (DI-1);
  float Ads = -__expf(A_log[d*16 + s]);
  size_t row0 = (size_t)b * LSEQ + (size_t)c * STEPS;
  const float* dp = delta + row0*DI + d;
  const float* up = u     + row0*DI + d;
  const float* xp = xdb   + row0*32 + s;
  float a = 1.f, bb = 0.f;
  #pragma unroll 8
  for (int t = 0; t < STEPS; ++t) {
    float dl = dp[(size_t)t*DI];
    float uu = up[(size_t)t*DI];
    float Bv = xp[t*32];
    float dA = __expf(dl * Ads);
    bb = fmaf(dA, bb, dl * uu * Bv);
    a *= dA;
  }
  int idx = c*PLANE + ch*16 + s;
  agg_a[idx] = a;
  agg_b[idx] = bb;
}

// pass 2: sequential scan over chunk aggregates -> h at each chunk start
__global__ __launch_bounds__(256) void scan_p2(const float* __restrict__ agg_a,
    const float* __restrict__ agg_b, float* __restrict__ hinit)
{
  int idx = blockIdx.x * 256 + threadIdx.x;   // 0..PLANE-1
  float h = 0.f;
  #pragma unroll
  for (int c = 0; c < SCHUNK; ++c) {
    hinit[c*PLANE + idx] = h;
    h = fmaf(agg_a[c*PLANE + idx], h, agg_b[c*PLANE + idx]);
  }
}

// pass 3: replay within chunk from hinit, reduce over 16 states, gated epilogue
__global__ __launch_bounds__(256) void scan_p3(const float* __restrict__ delta,
    const float* __restrict__ u, const float* __restrict__ xdb,
    const float* __restrict__ A_log, const float* __restrict__ Dp,
    const float* __restrict__ xz, const float* __restrict__ hinit,
    unsigned short* __restrict__ y_bf)
{
  int tid = threadIdx.x;
  int s = tid & 15, g = tid >> 4;
  int ch = blockIdx.x * 16 + g;
  int c  = blockIdx.y;
  int b = ch >> 11, d = ch & (DI-1);
  float Ads = -__expf(A_log[d*16 + s]);
  float Dd  = Dp[d];
  float h = hinit[c*PLANE + ch*16 + s];
  size_t row0 = (size_t)b * LSEQ + (size_t)c * STEPS;
  for (int t0 = 0; t0 < STEPS; t0 += 8) {
    float y8[8];
    #pragma unroll
    for (int t = 0; t < 8; ++t) {
      size_t row = row0 + t0 + t;
      float dl = delta[row*DI + d];
      float uu = u[row*DI + d];
      float Bv = xdb[row*32 + s];
      float Cv = xdb[row*32 + 16 + s];
      float dA = __expf(dl * Ads);
      h = fmaf(dA, h, dl * uu * Bv);
      y8[t] = h * Cv;
    }
    #pragma unroll
    for (int t = 0; t < 8; ++t) {
      float p = y8[t];
      p += __shfl_xor(p, 8);
      p += __shfl_xor(p, 4);
      p += __shfl_xor(p, 2);
      p += __shfl_xor(p, 1);
      y8[t] = p;
    }
    if (s == 0) {
      #pragma unroll
      for (int t = 0; t < 8; ++t) {
        size_t row = row0 + t0 + t;
        float uu = u[row*DI + d];
        float zz = xz[row*(2*DI) + DI + d];
        float yv = y8[t] + uu * Dd;
        yv *= zz / (1.f + __expf(-zz));
        y_bf[row*DI + d] = f2bf(yv);
      }
    }
  }
}

extern "C" void kernel_launch(void* const* d_in, const int* in_sizes, int n_in,
                              void* d_out, int out_size, void* d_ws, size_t ws_size,
                              hipStream_t stream)
{
  (void)in_sizes; (void)n_in; (void)out_size;
  const float* x      = (const float*)d_in[0];
  const float* norm_w = (const float*)d_in[1];
  const float* norm_b = (const float*)d_in[2];
  const float* in_w   = (const float*)d_in[3];
  const float* in_b   = (const float*)d_in[4];
  const float* conv_w = (const float*)d_in[5];
  const float* conv_b = (const float*)d_in[6];
  const float* xp_w   = (const float*)d_in[7];
  const float* xp_b   = (const float*)d_in[8];
  const float* dt_w   = (const float*)d_in[9];
  const float* dt_b   = (const float*)d_in[10];
  const float* A_log  = (const float*)d_in[11];
  const float* D_par  = (const float*)d_in[12];
  const float* out_w  = (const float*)d_in[13];
  const float* out_b  = (const float*)d_in[14];
  float* out = (float*)d_out;

  char* p = (char*)d_ws;
  unsigned short* xn_bf = (unsigned short*)p;  p += 2048ull*1024*2;
  unsigned short* w_in  = (unsigned short*)p;  p += 4096ull*1024*2;   // 8 MB
  unsigned short* w_dt  = (unsigned short*)p;  p += 2048ull*2048*2;   // 8 MB
  unsigned short* w_out = (unsigned short*)p;  p += 1024ull*2048*2;
  unsigned short* wx_bf = (unsigned short*)p;  p += 32ull*2048*2;     // 128 KB
  float*          xz    = (float*)p;           p += 2048ull*4096*4;
  float*          u_f   = (float*)p;           p += 2048ull*2048*4;
  unsigned short* u_bf  = (unsigned short*)p;  p += 2048ull*2048*2;   // 8 MB
  float*          xdb   = (float*)p;           p += 2048ull*32*4;
  float*          delta = (float*)p;           p += 2048ull*2048*4;
  unsigned short* y_bf  = (unsigned short*)p;  p += 2048ull*2048*2;
  if ((size_t)(p - (char*)d_ws) > ws_size) return;  // ws too small: fail visibly

  // scan scratch overlays regions that are dead by scan time:
  //   w_in  (dead after gemm<0>)  -> agg_a (8 MB)
  //   w_dt  (dead after gemm<1>)  -> agg_b (8 MB)
  //   u_bf  (dead after gemm<1>)  -> hinit (8 MB)
  float* agg_a = (float*)w_in;
  float* agg_b = (float*)w_dt;
  float* hinit = (float*)u_bf;

  ln_cast<<<MROWS, 256, 0, stream>>>(x, norm_w, norm_b, xn_bf);
  castk<<<2048, 256, 0, stream>>>(in_w,  w_in,  4096*1024/4);
  castk<<<2048, 256, 0, stream>>>(dt_w,  w_dt,  2048*2048/4);
  castk<<<1024, 256, 0, stream>>>(out_w, w_out, 1024*2048/4);
  castk<<<64,   256, 0, stream>>>(xp_w,  wx_bf, 32*2048/4);

  gemm_bt<0><<<dim3(4096/128, MROWS/128), 256, 0, stream>>>(xn_bf, w_in, in_b, nullptr, xz, 4096, 1024);
  conv_silu<<<(MROWS*DI)/256, 256, 0, stream>>>(xz, conv_w, conv_b, u_f, u_bf);
  xproj_mfma<<<MROWS/16, 64, 0, stream>>>(u_bf, wx_bf, xp_b, xdb);
  gemm_bt<1><<<dim3(2048/128, MROWS/128), 256, 0, stream>>>(u_bf, w_dt, dt_b, nullptr, delta, 2048, 2048);

  scan_p1<<<dim3(NCH/16, SCHUNK), 256, 0, stream>>>(delta, u_f, xdb, A_log, agg_a, agg_b);
  scan_p2<<<PLANE/256, 256, 0, stream>>>(agg_a, agg_b, hinit);
  scan_p3<<<dim3(NCH/16, SCHUNK), 256, 0, stream>>>(delta, u_f, xdb, A_log, D_par, xz, hinit, y_bf);

  gemm_bt<2><<<dim3(1024/128, MROWS/128), 256, 0, stream>>>(y_bf, w_out, out_b, x, out, 1024, 2048);
}